// Round 5
// baseline (158.905 us; speedup 1.0000x reference)
//
#include <hip/hip_runtime.h>

// Problem: B=16, C=4, H=W=512. input [B,C,H,W] f32; target [B,C+1,H,W] f32,
// last channel a {0,1} mask. Output scalar:
//   (1/B) * sum_b [ cnt_b>0 ? sum_{c,hw} mask*(in-tg)^2 / (C*cnt_b) : 0 ]
//
// History: R7 (166.0): 3 streams/block, XCD-swizzle, nt in/tg. R8 (160.1):
// no memset/atomics. R9 (156.3): 2048 blocks, 32 waves/CU. R10 (168.5):
// nt removed -> +12 us REGRESSION (nt load-bearing on read path).
// R11 (155.9): mask nt too — neutral-positive; keep.
// Evidence synthesis: partial ~44 us = 202 MB of CU read *requests* at
// ~4.6 TB/s (HBM FETCH only 74 MB — LLC serves the rest; HBM not the
// limiter). Occupancy and burst depth ablated neutral => per-CU
// outstanding-request path is saturated. Remaining lever: request COUNT.
// R12 (this round): merge 4 channels into one block — 9 streams
// (mask + 4 in + 4 tg). Mask requested once instead of 4x:
// 202 -> 151 MB requests (-25%). Drops XCD swizzle + c==0 special-case
// (each unit computes cnt exactly once). CHUNK 2048 px -> 2048 blocks
// (8/CU), 2 iters/thread, 9-load bursts (~36 data VGPRs).

#define BATCH 16
#define CHAN 4
#define HWPIX (512 * 512)                 // 262144 pixels per plane
#define CHUNK_PX 2048                     // pixels per chunk
#define CPB (HWPIX / CHUNK_PX)            // 128 chunks per plane
#define UNITS (BATCH * CPB)               // 2048 (b,k) units = blocks
#define THREADS 256
#define G4 (CHUNK_PX / 4)                 // 512 float4 per chunk-plane
#define ITERS (G4 / THREADS)              // 2 iterations per thread

// ws layout: [0, 2048)        S slot per unit at b*CPB + k
//            [2048, 4096)     cnt slot per unit at b*CPB + k
#define WS_CNT_BASE UNITS

typedef float vf4 __attribute__((ext_vector_type(4)));

__global__ __launch_bounds__(THREADS, 8) void masked_mse_partial(
    const float* __restrict__ input,
    const float* __restrict__ target,
    float* __restrict__ ws) {
    const int u = blockIdx.x;             // [0, 2048)
    const int b = u >> 7;                 // u / CPB
    const int k = u & (CPB - 1);

    // 9 streams: mask + {in,tg} x 4 channels. Plane stride HWPIX.
    const vf4* i0 = (const vf4*)(input  + ((size_t)b * CHAN) * HWPIX
                                        + (size_t)k * CHUNK_PX);
    const vf4* t0 = (const vf4*)(target + ((size_t)b * (CHAN + 1)) * HWPIX
                                        + (size_t)k * CHUNK_PX);
    const vf4* mp = t0 + (size_t)CHAN * (HWPIX / 4);

    float s = 0.f, cnt = 0.f;

#pragma unroll
    for (int it = 0; it < ITERS; ++it) {
        const int g = it * THREADS + threadIdx.x;
        // 9-load burst: all requests issued before any use (~36 data VGPRs)
        vf4 m  = __builtin_nontemporal_load(&mp[g]);
        vf4 a0 = __builtin_nontemporal_load(&i0[g]);
        vf4 a1 = __builtin_nontemporal_load(&i0[g + (HWPIX / 4)]);
        vf4 a2 = __builtin_nontemporal_load(&i0[g + 2 * (HWPIX / 4)]);
        vf4 a3 = __builtin_nontemporal_load(&i0[g + 3 * (HWPIX / 4)]);
        vf4 b0 = __builtin_nontemporal_load(&t0[g]);
        vf4 b1 = __builtin_nontemporal_load(&t0[g + (HWPIX / 4)]);
        vf4 b2 = __builtin_nontemporal_load(&t0[g + 2 * (HWPIX / 4)]);
        vf4 b3 = __builtin_nontemporal_load(&t0[g + 3 * (HWPIX / 4)]);

        vf4 d0 = a0 - b0, d1 = a1 - b1, d2 = a2 - b2, d3 = a3 - b3;
        vf4 acc = (d0 * d0 + d1 * d1 + d2 * d2 + d3 * d3) * m;
        s += acc.x + acc.y + acc.z + acc.w;
        cnt += m.x + m.y + m.z + m.w;
    }

    // wave-64 shuffle reduction
#pragma unroll
    for (int off = 32; off > 0; off >>= 1) {
        s   += __shfl_down(s, off, 64);
        cnt += __shfl_down(cnt, off, 64);
    }

    __shared__ float ss[THREADS / 64];
    __shared__ float sc[THREADS / 64];
    const int lane = threadIdx.x & 63;
    const int wid  = threadIdx.x >> 6;
    if (lane == 0) { ss[wid] = s; sc[wid] = cnt; }
    __syncthreads();

    if (threadIdx.x == 0) {
        float S = 0.f, Cn = 0.f;
#pragma unroll
        for (int w = 0; w < THREADS / 64; ++w) { S += ss[w]; Cn += sc[w]; }
        // unique slot per block -> no memset, no atomics, poison-safe
        ws[u] = S;
        ws[WS_CNT_BASE + u] = Cn;
    }
}

__global__ __launch_bounds__(256) void masked_mse_final(
    const float* __restrict__ ws,
    float* __restrict__ out) {
    // 256 threads = 16 groups of 16 lanes; group g handles batch b=g.
    // Each batch has 128 S slots and 128 cnt slots.
    const int t = threadIdx.x;
    const int g = t >> 4;                 // batch
    const int j = t & 15;

    float S = 0.f, Cn = 0.f;
#pragma unroll
    for (int i = 0; i < 8; ++i) {
        S  += ws[g * CPB + j * 8 + i];
        Cn += ws[WS_CNT_BASE + g * CPB + j * 8 + i];
    }

    // reduce within each 16-lane group (all inside one wave-64)
#pragma unroll
    for (int off = 8; off > 0; off >>= 1) {
        S  += __shfl_down(S,  off, 16);
        Cn += __shfl_down(Cn, off, 16);
    }

    __shared__ float per_b[BATCH];
    if (j == 0) {
        float cb = Cn * (float)CHAN;      // C * #masked pixels
        per_b[g] = (cb > 0.f) ? (S / cb) : 0.f;
    }
    __syncthreads();

    if (t == 0) {
        float acc = 0.f;
#pragma unroll
        for (int b = 0; b < BATCH; ++b) acc += per_b[b];
        out[0] = acc / (float)BATCH;
    }
}

extern "C" void kernel_launch(void* const* d_in, const int* in_sizes, int n_in,
                              void* d_out, int out_size, void* d_ws, size_t ws_size,
                              hipStream_t stream) {
    const float* input  = (const float*)d_in[0];
    const float* target = (const float*)d_in[1];
    float* out = (float*)d_out;
    float* ws  = (float*)d_ws;

    masked_mse_partial<<<dim3(UNITS), dim3(THREADS), 0, stream>>>(
        input, target, ws);
    masked_mse_final<<<1, 256, 0, stream>>>(ws, out);
}

// Round 6
// 156.461 us; speedup vs baseline: 1.0156x; 1.0156x over previous
//
#include <hip/hip_runtime.h>

// Problem: B=16, C=4, H=W=512. input [B,C,H,W] f32; target [B,C+1,H,W] f32,
// last channel a {0,1} mask. Output scalar:
//   (1/B) * sum_b [ cnt_b>0 ? sum_{c,hw} mask*(in-tg)^2 / (C*cnt_b) : 0 ]
//
// History: R7 (166.0): 3 streams/block, XCD-swizzle, nt in/tg. R8 (160.1):
// no memset/atomics. R9 (156.3): 2048 blocks, 32 waves/CU. R10 (168.5):
// nt removed -> +12 us REGRESSION (nt load-bearing). R11 (155.9, BEST):
// all-nt. R12 (158.9): 9-stream merge REGRESSION -> request count not the
// limiter; reverted.
// Model: 151 MB coalesced reads @ 3.4 TB/s = 5.6 B/cyc/CU with VALUBusy
// 3.6%, occupancy+depth neutral => fixed per-CU outstanding-line budget in
// the L1/TCP miss path (~64 lines x 64B / ~675 cyc LLC-HBM mix). L1 is
// useless here (every line consumed once per block; mask reuse is via
// L2/LLC).
// R13 (this round): R11 geometry + ONE delta: loads issued as inline-asm
//   global_load_dwordx4 ... sc0 nt
// (scope-elevated -> L1 bypass, L2 still allocates) with explicit
// s_waitcnt vmcnt(0) + sched_barrier(0) before use (rule #18: asm loads
// have no compiler waitcnt tracking; fence stops use-hoisting).
// Falsifier: neutral/regression => per-CU read path HW-saturated; revert
// to R11 and call roofline.

#define BATCH 16
#define CHAN 4
#define HWPIX (512 * 512)                 // 262144 pixels per plane
#define CHUNK_PX 8192                     // pixels per chunk
#define CPB (HWPIX / CHUNK_PX)            // 32 chunks per plane
#define UNITS (BATCH * CPB)               // 512 (b,k) units
#define THREADS 256
#define TOTAL_BLOCKS (UNITS * CHAN)       // 2048 blocks = 8 per CU
#define G4 (CHUNK_PX / 4)                 // 2048 float4 per chunk-plane
#define ITERS (G4 / THREADS)              // 8 iterations per thread

// ws layout: [0, 2048)        S slot per block  at (b*4 + c)*32 + k
//            [2048, 2048+512) cnt slot per unit at b*32 + k   (c==0 blocks)
#define WS_CNT_BASE (UNITS * CHAN)

typedef float vf4 __attribute__((ext_vector_type(4)));

// L1-bypass streaming load: scope-elevated (sc0) + non-temporal (nt).
// NOTE: no compiler waitcnt tracking — caller MUST s_waitcnt vmcnt(0)
// + sched_barrier(0) before consuming results.
__device__ __forceinline__ vf4 ld_sc0_nt(const vf4* p) {
    vf4 r;
    asm volatile("global_load_dwordx4 %0, %1, off sc0 nt"
                 : "=v"(r) : "v"(p));
    return r;
}

__global__ __launch_bounds__(THREADS, 8) void masked_mse_partial(
    const float* __restrict__ input,
    const float* __restrict__ target,
    float* __restrict__ ws) {
    // blockIdx swizzle: idx = q*32 + c*8 + r. All four c-blocks of unit
    // u=(q,r) are congruent mod 8 -> same XCD, dispatched within a 32-block
    // window -> mask chunk L2-hits on 3 of 4 reads.
    const int bid = blockIdx.x;
    const int r   = bid & 7;
    const int c   = (bid >> 3) & 3;
    const int q   = bid >> 5;             // [0, 64)
    const int u   = q * 8 + r;            // [0, 512)
    const int b   = u >> 5;               // u / CPB
    const int k   = u & (CPB - 1);

    const vf4* ip = (const vf4*)(input  + ((size_t)b * CHAN + c) * HWPIX
                                        + (size_t)k * CHUNK_PX);
    const vf4* tp = (const vf4*)(target + ((size_t)b * (CHAN + 1) + c) * HWPIX
                                        + (size_t)k * CHUNK_PX);
    const vf4* mp = (const vf4*)(target + ((size_t)b * (CHAN + 1) + CHAN) * HWPIX
                                        + (size_t)k * CHUNK_PX);

    float s = 0.f, cnt = 0.f;

    // 6-load sc0+nt bursts (2 iters x 3 streams); explicit drain before use.
    for (int it = 0; it < ITERS; it += 2) {
        const int g0 = it * THREADS + threadIdx.x;
        vf4 a0 = ld_sc0_nt(&ip[g0]);
        vf4 a1 = ld_sc0_nt(&ip[g0 + THREADS]);
        vf4 t0 = ld_sc0_nt(&tp[g0]);
        vf4 t1 = ld_sc0_nt(&tp[g0 + THREADS]);
        vf4 m0 = ld_sc0_nt(&mp[g0]);
        vf4 m1 = ld_sc0_nt(&mp[g0 + THREADS]);

        asm volatile("s_waitcnt vmcnt(0)" ::: "memory");
        __builtin_amdgcn_sched_barrier(0);

        vf4 d0 = a0 - t0, d1 = a1 - t1;
        vf4 acc = d0 * d0 * m0 + d1 * d1 * m1;
        s += acc.x + acc.y + acc.z + acc.w;

        if (c == 0) {   // wave-uniform: count mask once per (b,k) unit
            vf4 mc = m0 + m1;
            cnt += mc.x + mc.y + mc.z + mc.w;
        }
    }

    // wave-64 shuffle reduction
#pragma unroll
    for (int off = 32; off > 0; off >>= 1) {
        s   += __shfl_down(s, off, 64);
        cnt += __shfl_down(cnt, off, 64);
    }

    __shared__ float ss[THREADS / 64];
    __shared__ float sc[THREADS / 64];
    const int lane = threadIdx.x & 63;
    const int wid  = threadIdx.x >> 6;
    if (lane == 0) { ss[wid] = s; sc[wid] = cnt; }
    __syncthreads();

    if (threadIdx.x == 0) {
        float S = 0.f, Cn = 0.f;
#pragma unroll
        for (int w = 0; w < THREADS / 64; ++w) { S += ss[w]; Cn += sc[w]; }
        // unique slot per block -> no memset, no atomics, poison-safe
        ws[(b * CHAN + c) * CPB + k] = S;
        if (c == 0) ws[WS_CNT_BASE + b * CPB + k] = Cn;
    }
}

__global__ __launch_bounds__(256) void masked_mse_final(
    const float* __restrict__ ws,
    float* __restrict__ out) {
    // 256 threads = 16 groups of 16 lanes; group g handles batch b=g.
    // Each batch has 128 S slots (4 c * 32 k) and 32 cnt slots.
    const int t = threadIdx.x;
    const int g = t >> 4;                 // batch
    const int j = t & 15;

    float S = 0.f;
#pragma unroll
    for (int i = 0; i < 8; ++i) S += ws[g * 128 + j * 8 + i];
    float Cn = ws[WS_CNT_BASE + g * 32 + j * 2]
             + ws[WS_CNT_BASE + g * 32 + j * 2 + 1];

    // reduce within each 16-lane group (all inside one wave-64)
#pragma unroll
    for (int off = 8; off > 0; off >>= 1) {
        S  += __shfl_down(S,  off, 16);
        Cn += __shfl_down(Cn, off, 16);
    }

    __shared__ float per_b[BATCH];
    if (j == 0) {
        float cb = Cn * (float)CHAN;      // C * #masked pixels
        per_b[g] = (cb > 0.f) ? (S / cb) : 0.f;
    }
    __syncthreads();

    if (t == 0) {
        float acc = 0.f;
#pragma unroll
        for (int b = 0; b < BATCH; ++b) acc += per_b[b];
        out[0] = acc / (float)BATCH;
    }
}

extern "C" void kernel_launch(void* const* d_in, const int* in_sizes, int n_in,
                              void* d_out, int out_size, void* d_ws, size_t ws_size,
                              hipStream_t stream) {
    const float* input  = (const float*)d_in[0];
    const float* target = (const float*)d_in[1];
    float* out = (float*)d_out;
    float* ws  = (float*)d_ws;

    masked_mse_partial<<<dim3(TOTAL_BLOCKS), dim3(THREADS), 0, stream>>>(
        input, target, ws);
    masked_mse_final<<<1, 256, 0, stream>>>(ws, out);
}